// Round 3
// baseline (872.895 us; speedup 1.0000x reference)
//
#include <hip/hip_runtime.h>

// GraphSAGE 2-layer, mean aggregation, d = 32.
// Atomic-free pipeline: radix-partition edges by dst>>7 into 128-node buckets
// (LDS histograms + deterministic scans), then one block per bucket does
// LDS-accumulated gather-mean + dual 32x32 GEMM + bias + relu, fully fused.

constexpr int D = 32;
constexpr int NPB = 128;                 // nodes per bucket
constexpr int LOG_NPB = 7;
constexpr int MAXB = 1024;               // max buckets (needs n <= 131072)
constexpr int NB = 640;                  // partition blocks
constexpr int SRC_BITS = 17;             // src id fits 17 bits (n <= 131072)
constexpr unsigned SRC_MASK = (1u << SRC_BITS) - 1;

// ---- Pass 1: per-block bucket histogram ----
__global__ void count_kernel(const int* __restrict__ dst, int* __restrict__ blockCnt,
                             int E, int B, int chunk) {
    __shared__ int hist[MAXB];
    int t = threadIdx.x;  // 256
    for (int b = t; b < B; b += 256) hist[b] = 0;
    __syncthreads();
    int base = blockIdx.x * chunk;
    int end = min(base + chunk, E);
    for (int e = base + t; e < end; e += 256)
        atomicAdd(&hist[dst[e] >> LOG_NPB], 1);
    __syncthreads();
    for (int b = t; b < B; b += 256)
        blockCnt[b * NB + blockIdx.x] = hist[b];
}

// ---- Pass 2a: per-bucket exclusive scan over blocks (in place) + totals ----
__global__ void scan_rows(int* __restrict__ blockCnt, int* __restrict__ bucketTotal, int B) {
    __shared__ int s[256];
    int t = threadIdx.x;
    int* row = blockCnt + blockIdx.x * NB;
    int carry = 0;
    for (int c = 0; c < NB; c += 256) {
        int i = c + t;
        int v = (i < NB) ? row[i] : 0;
        s[t] = v;
        __syncthreads();
        for (int off = 1; off < 256; off <<= 1) {
            int x = (t >= off) ? s[t - off] : 0;
            __syncthreads();
            s[t] += x;
            __syncthreads();
        }
        int incl = s[t];
        int total = s[255];
        __syncthreads();              // s reused next chunk
        if (i < NB) row[i] = carry + incl - v;
        carry += total;
    }
    if (t == 0) bucketTotal[blockIdx.x] = carry;
}

// ---- Pass 2b: exclusive scan over bucket totals -> bucketBase[B+1] ----
__global__ void scan_buckets(const int* __restrict__ bucketTotal, int* __restrict__ bucketBase,
                             int B, int E) {
    __shared__ int s[256];
    int t = threadIdx.x;
    int carry = 0;
    for (int c = 0; c < MAXB; c += 256) {
        int i = c + t;
        int v = (i < B) ? bucketTotal[i] : 0;
        s[t] = v;
        __syncthreads();
        for (int off = 1; off < 256; off <<= 1) {
            int x = (t >= off) ? s[t - off] : 0;
            __syncthreads();
            s[t] += x;
            __syncthreads();
        }
        int incl = s[t];
        int total = s[255];
        __syncthreads();
        if (i < B) bucketBase[i] = carry + incl - v;
        carry += total;
    }
    if (t == 0) bucketBase[B] = E;
}

// ---- Pass 3: scatter packed edges into bucketed order (LDS cursors only) ----
__global__ void partition_kernel(const int* __restrict__ src, const int* __restrict__ dst,
                                 const int* __restrict__ blockCnt,
                                 const int* __restrict__ bucketBase,
                                 unsigned* __restrict__ ebuf, int E, int B, int chunk) {
    __shared__ int cursor[MAXB];
    int t = threadIdx.x;  // 256
    for (int b = t; b < B; b += 256)
        cursor[b] = bucketBase[b] + blockCnt[b * NB + blockIdx.x];
    __syncthreads();
    int base = blockIdx.x * chunk;
    int end = min(base + chunk, E);
    for (int e = base + t; e < end; e += 256) {
        int d = dst[e];
        int bkt = d >> LOG_NPB;
        int pos = atomicAdd(&cursor[bkt], 1);    // LDS atomic, low contention
        ebuf[pos] = ((unsigned)(d & (NPB - 1)) << SRC_BITS) | (unsigned)src[e];
    }
}

// ---- Fused SAGE layer: one block per bucket ----
// 512 threads = 16 groups x 32 lanes (lane j = feature j).
__global__ __launch_bounds__(512, 4)
void sage_bucket(const float* __restrict__ xin,
                 const int* __restrict__ bucketBase,
                 const unsigned* __restrict__ ebuf,
                 const float* __restrict__ Wl, const float* __restrict__ Wr,
                 const float* __restrict__ bias,
                 float* __restrict__ out, int n) {
    __shared__ float acc[NPB * D];    // 16 KB aggregation accumulators
    __shared__ float xloc[NPB * D];   // 16 KB this bucket's own x rows
    __shared__ float cnt[NPB];        // degrees
    __shared__ float sWl[D * D];      // 4 KB
    __shared__ float sWr[D * D];      // 4 KB
    int t = threadIdx.x;              // 512
    int node0 = blockIdx.x * NPB;
#pragma unroll
    for (int i = 0; i < 8; ++i) acc[t + i * 512] = 0.f;
    if (t < NPB) cnt[t] = 0.f;
#pragma unroll
    for (int i = 0; i < 2; ++i) {
        sWl[t + i * 512] = Wl[t + i * 512];
        sWr[t + i * 512] = Wr[t + i * 512];
    }
#pragma unroll
    for (int i = 0; i < 8; ++i) {
        int idx = t + i * 512;                         // 0..4095
        int gn = node0 + (idx >> 5);
        xloc[idx] = (gn < n) ? xin[(size_t)node0 * D + idx] : 0.f;
    }
    __syncthreads();

    int g = t >> 5, j = t & 31;
    int base = bucketBase[blockIdx.x];
    int end = bucketBase[blockIdx.x + 1];
    int e = base + g;
    // 2x unrolled edge stream: independent gathers issued together
    for (; e + 16 < end; e += 32) {
        unsigned w1 = ebuf[e], w2 = ebuf[e + 16];
        int s1 = w1 & SRC_MASK, s2 = w2 & SRC_MASK;
        int d1 = w1 >> SRC_BITS, d2 = w2 >> SRC_BITS;
        float v1 = xin[(size_t)s1 * D + j];            // one 128B line per group
        float v2 = xin[(size_t)s2 * D + j];
        atomicAdd(&acc[d1 * D + j], v1);               // LDS ds_add_f32, bank-clean
        atomicAdd(&acc[d2 * D + j], v2);
        if (j == 0) { atomicAdd(&cnt[d1], 1.f); atomicAdd(&cnt[d2], 1.f); }
    }
    if (e < end) {
        unsigned w = ebuf[e];
        int s1 = w & SRC_MASK, d1 = w >> SRC_BITS;
        atomicAdd(&acc[d1 * D + j], xin[(size_t)s1 * D + j]);
        if (j == 0) atomicAdd(&cnt[d1], 1.f);
    }
    __syncthreads();

    float bj = bias[j];
#pragma unroll
    for (int it = 0; it < NPB / 16; ++it) {            // 8 x 16 nodes
        int dl = it * 16 + g;
        int gn = node0 + dl;
        if (gn < n) {
            float accA = 0.f, accX = 0.f;
            const float* ar = acc + dl * D;            // broadcast reads
            const float* xr = xloc + dl * D;
#pragma unroll
            for (int k = 0; k < D; ++k) {
                accA += ar[k] * sWl[k * D + j];
                accX += xr[k] * sWr[k * D + j];
            }
            float rdeg = 1.f / fmaxf(cnt[dl], 1.f);
            out[(size_t)gn * D + j] = fmaxf(accA * rdeg + bj + accX, 0.f);
        }
    }
}

extern "C" void kernel_launch(void* const* d_in, const int* in_sizes, int n_in,
                              void* d_out, int out_size, void* d_ws, size_t ws_size,
                              hipStream_t stream) {
    const float* x   = (const float*)d_in[0];
    const int*   ei  = (const int*)d_in[1];
    const float* W1l = (const float*)d_in[2];
    const float* W1r = (const float*)d_in[3];
    const float* b1  = (const float*)d_in[4];
    const float* W2l = (const float*)d_in[5];
    const float* W2r = (const float*)d_in[6];
    const float* b2  = (const float*)d_in[7];
    float* out = (float*)d_out;

    const int n = in_sizes[0] / D;
    const int E = in_sizes[1] / 2;
    const int* src = ei;
    const int* dst = ei + E;
    const int B = (n + NPB - 1) >> LOG_NPB;     // 782 for n=100000
    const int chunk = (E + NB - 1) / NB;

    // ws: blockCnt[MAXB*NB] | bucketTotal[MAXB] | bucketBase[MAXB+1] | ebuf[E] | h[n*D]
    int* blockCnt    = (int*)d_ws;
    int* bucketTotal = blockCnt + (size_t)MAXB * NB;
    int* bucketBase  = bucketTotal + MAXB;
    unsigned* ebuf   = (unsigned*)(bucketBase + (MAXB + 1));
    float* h         = (float*)(ebuf + E);

    count_kernel<<<NB, 256, 0, stream>>>(dst, blockCnt, E, B, chunk);
    scan_rows<<<B, 256, 0, stream>>>(blockCnt, bucketTotal, B);
    scan_buckets<<<1, 256, 0, stream>>>(bucketTotal, bucketBase, B, E);
    partition_kernel<<<NB, 256, 0, stream>>>(src, dst, blockCnt, bucketBase, ebuf, E, B, chunk);

    sage_bucket<<<B, 512, 0, stream>>>(x, bucketBase, ebuf, W1l, W1r, b1, h, n);
    sage_bucket<<<B, 512, 0, stream>>>(h, bucketBase, ebuf, W2l, W2r, b2, out, n);
}

// Round 4
// 801.859 us; speedup vs baseline: 1.0886x; 1.0886x over previous
//
#include <hip/hip_runtime.h>

// GraphSAGE 2-layer, mean aggregation, d = 32.
// Atomic-free (global) pipeline: radix-partition edges by dst>>6 into 64-node
// buckets, then one block per bucket: LDS-staged edge stream, 8-deep unrolled
// 128B gathers, LDS f32 accumulation, fused dual 32x32 GEMM + bias + relu.

constexpr int D = 32;
constexpr int NPB = 64;                  // nodes per bucket
constexpr int LOG_NPB = 6;
constexpr int MAXB = 1600;               // max buckets (n <= 102400)
constexpr int NB = 320;                  // partition blocks
constexpr int SRC_BITS = 17;             // src id fits 17 bits
constexpr unsigned SRC_MASK = (1u << SRC_BITS) - 1;
constexpr int STAGE = 2048;              // staged edges per chunk (multiple of 64)
constexpr unsigned DUMMY = ((unsigned)NPB << SRC_BITS);  // trash row 64, src 0

// ---- Pass 1: per-block bucket histogram ----
__global__ void count_kernel(const int* __restrict__ dst, int* __restrict__ blockCnt,
                             int E, int B, int chunk) {
    __shared__ int hist[MAXB];
    int t = threadIdx.x;  // 256
    for (int b = t; b < B; b += 256) hist[b] = 0;
    __syncthreads();
    int base = blockIdx.x * chunk;
    int end = min(base + chunk, E);
    for (int e = base + t; e < end; e += 256)
        atomicAdd(&hist[dst[e] >> LOG_NPB], 1);
    __syncthreads();
    for (int b = t; b < B; b += 256)
        blockCnt[b * NB + blockIdx.x] = hist[b];
}

// ---- Pass 2a: per-bucket exclusive scan over blocks (in place) + totals ----
__global__ void scan_rows(int* __restrict__ blockCnt, int* __restrict__ bucketTotal, int B) {
    __shared__ int s[256];
    int t = threadIdx.x;
    int* row = blockCnt + blockIdx.x * NB;
    int carry = 0;
    for (int c = 0; c < NB; c += 256) {
        int i = c + t;
        int v = (i < NB) ? row[i] : 0;
        s[t] = v;
        __syncthreads();
        for (int off = 1; off < 256; off <<= 1) {
            int x = (t >= off) ? s[t - off] : 0;
            __syncthreads();
            s[t] += x;
            __syncthreads();
        }
        int incl = s[t];
        int total = s[255];
        __syncthreads();
        if (i < NB) row[i] = carry + incl - v;
        carry += total;
    }
    if (t == 0) bucketTotal[blockIdx.x] = carry;
}

// ---- Pass 2b: exclusive scan over bucket totals -> bucketBase[B+1] ----
__global__ void scan_buckets(const int* __restrict__ bucketTotal, int* __restrict__ bucketBase,
                             int B, int E) {
    __shared__ int s[256];
    int t = threadIdx.x;
    int carry = 0;
    for (int c = 0; c < MAXB; c += 256) {
        int i = c + t;
        int v = (i < B) ? bucketTotal[i] : 0;
        s[t] = v;
        __syncthreads();
        for (int off = 1; off < 256; off <<= 1) {
            int x = (t >= off) ? s[t - off] : 0;
            __syncthreads();
            s[t] += x;
            __syncthreads();
        }
        int incl = s[t];
        int total = s[255];
        __syncthreads();
        if (i < B) bucketBase[i] = carry + incl - v;
        carry += total;
    }
    if (t == 0) bucketBase[B] = E;
}

// ---- Pass 3: scatter packed edges into bucketed order (LDS cursors only) ----
__global__ void partition_kernel(const int* __restrict__ src, const int* __restrict__ dst,
                                 const int* __restrict__ blockCnt,
                                 const int* __restrict__ bucketBase,
                                 unsigned* __restrict__ ebuf, int E, int B, int chunk) {
    __shared__ int cursor[MAXB];
    int t = threadIdx.x;  // 256
    for (int b = t; b < B; b += 256)
        cursor[b] = bucketBase[b] + blockCnt[b * NB + blockIdx.x];
    __syncthreads();
    int base = blockIdx.x * chunk;
    int end = min(base + chunk, E);
    for (int e = base + t; e < end; e += 256) {
        int d = dst[e];
        int bkt = d >> LOG_NPB;
        int pos = atomicAdd(&cursor[bkt], 1);    // LDS atomic, low contention
        ebuf[pos] = ((unsigned)(d & (NPB - 1)) << SRC_BITS) | (unsigned)src[e];
    }
}

// ---- Fused SAGE layer: one block (256 thr = 8 groups x 32 lanes) per bucket ----
__global__ __launch_bounds__(256, 4)
void sage_bucket(const float* __restrict__ xin,
                 const int* __restrict__ bucketBase,
                 const unsigned* __restrict__ ebuf,
                 const float* __restrict__ Wl, const float* __restrict__ Wr,
                 const float* __restrict__ bias,
                 float* __restrict__ out, int n) {
    __shared__ float acc[(NPB + 1) * D];     // 8.125 KB (+1 trash row for pad edges)
    __shared__ unsigned stage[STAGE];        // 8 KB; reused as xloc in epilogue
    __shared__ float sWl[D * D];             // 4 KB
    __shared__ float sWr[D * D];             // 4 KB
    __shared__ int cntI[NPB];                // degrees
    int t = threadIdx.x;
    int node0 = blockIdx.x * NPB;

    for (int i = t; i < (NPB + 1) * D; i += 256) acc[i] = 0.f;
    if (t < NPB) cntI[t] = 0;
#pragma unroll
    for (int i = 0; i < 4; ++i) {
        sWl[t + i * 256] = Wl[t + i * 256];
        sWr[t + i * 256] = Wr[t + i * 256];
    }

    int g = t >> 5, j = t & 31;
    int base = bucketBase[blockIdx.x];
    int end = bucketBase[blockIdx.x + 1];

    while (base < end) {
        int len = min(end - base, STAGE);
        int lenp = (len + 63) & ~63;         // pad to 64 with dummy edges
        __syncthreads();                     // init/prev-chunk reads done; stage free
        for (int i = t; i < lenp; i += 256) {
            unsigned w = DUMMY;
            if (i < len) {
                w = ebuf[base + i];
                atomicAdd(&cntI[w >> SRC_BITS], 1);
            }
            stage[i] = w;
        }
        __syncthreads();
        // 8 groups x 8 edges per iteration; guard-free (padded)
        for (int k0 = g * 8; k0 < lenp; k0 += 64) {
            unsigned w[8];
            float v[8];
#pragma unroll
            for (int u = 0; u < 8; ++u) w[u] = stage[k0 + u];       // LDS broadcast
#pragma unroll
            for (int u = 0; u < 8; ++u)                              // 8 lines in flight
                v[u] = xin[(size_t)(w[u] & SRC_MASK) * D + j];
#pragma unroll
            for (int u = 0; u < 8; ++u)
                atomicAdd(&acc[(w[u] >> SRC_BITS) * D + j], v[u]);   // ds_add_f32
        }
        base += len;
    }

    __syncthreads();                         // all gathers done; stage reusable
    float* xloc = (float*)stage;
    for (int i = t; i < NPB * D; i += 256) {
        int gn = node0 + (i >> 5);
        xloc[i] = (gn < n) ? xin[(size_t)node0 * D + i] : 0.f;
    }
    __syncthreads();

    float bj = bias[j];
#pragma unroll
    for (int it = 0; it < NPB / 8; ++it) {
        int dl = it * 8 + g;
        int gn = node0 + dl;
        if (gn < n) {
            float accA = 0.f, accX = 0.f;
            const float* ar = acc + dl * D;  // broadcast reads
            const float* xr = xloc + dl * D;
#pragma unroll
            for (int k = 0; k < D; ++k) {
                accA += ar[k] * sWl[k * D + j];
                accX += xr[k] * sWr[k * D + j];
            }
            float rdeg = 1.f / fmaxf((float)cntI[dl], 1.f);
            out[(size_t)gn * D + j] = fmaxf(accA * rdeg + bj + accX, 0.f);
        }
    }
}

extern "C" void kernel_launch(void* const* d_in, const int* in_sizes, int n_in,
                              void* d_out, int out_size, void* d_ws, size_t ws_size,
                              hipStream_t stream) {
    const float* x   = (const float*)d_in[0];
    const int*   ei  = (const int*)d_in[1];
    const float* W1l = (const float*)d_in[2];
    const float* W1r = (const float*)d_in[3];
    const float* b1  = (const float*)d_in[4];
    const float* W2l = (const float*)d_in[5];
    const float* W2r = (const float*)d_in[6];
    const float* b2  = (const float*)d_in[7];
    float* out = (float*)d_out;

    const int n = in_sizes[0] / D;
    const int E = in_sizes[1] / 2;
    const int* src = ei;
    const int* dst = ei + E;
    const int B = (n + NPB - 1) >> LOG_NPB;     // 1563 for n=100000
    const int chunk = (E + NB - 1) / NB;

    // ws: blockCnt[MAXB*NB] | bucketTotal[MAXB] | bucketBase[MAXB+1] | ebuf[E] | h[n*D]
    int* blockCnt    = (int*)d_ws;
    int* bucketTotal = blockCnt + (size_t)MAXB * NB;
    int* bucketBase  = bucketTotal + MAXB;
    unsigned* ebuf   = (unsigned*)(bucketBase + (MAXB + 1));
    float* h         = (float*)(ebuf + E);

    count_kernel<<<NB, 256, 0, stream>>>(dst, blockCnt, E, B, chunk);
    scan_rows<<<B, 256, 0, stream>>>(blockCnt, bucketTotal, B);
    scan_buckets<<<1, 256, 0, stream>>>(bucketTotal, bucketBase, B, E);
    partition_kernel<<<NB, 256, 0, stream>>>(src, dst, blockCnt, bucketBase, ebuf, E, B, chunk);

    sage_bucket<<<B, 256, 0, stream>>>(x, bucketBase, ebuf, W1l, W1r, b1, h, n);
    sage_bucket<<<B, 256, 0, stream>>>(h, bucketBase, ebuf, W2l, W2r, b2, out, n);
}

// Round 5
// 230.978 us; speedup vs baseline: 3.7791x; 3.4716x over previous
//
#include <hip/hip_runtime.h>

// GraphSAGE 2-layer, mean aggregation, d = 32.
// Pipeline: radix-partition edges by dst>>6 into 64-node buckets (LDS int
// histograms + deterministic scans, no global atomics), then one block per
// bucket: LDS-staged edge stream, 8-deep unrolled 64B bf16 gathers,
// Q18 fixed-point LDS **int** accumulation (native ds_add_u32 — fp32 LDS
// atomicAdd compiles to a CAS loop and was the R3/R4 bottleneck),
// fused dual 32x32 GEMM + bias + relu.

constexpr int D = 32;
constexpr int NPB = 64;                  // nodes per bucket
constexpr int LOG_NPB = 6;
constexpr int MAXB = 1600;               // max buckets (n <= 102400)
constexpr int NB = 320;                  // partition blocks
constexpr int SRC_BITS = 17;             // src id fits 17 bits
constexpr unsigned SRC_MASK = (1u << SRC_BITS) - 1;
constexpr int STAGE = 1024;              // staged edges per chunk (mult of 64)
constexpr unsigned DUMMY = ((unsigned)NPB << SRC_BITS);  // trash row 64, src 0
constexpr float QS = 262144.0f;          // Q18 fixed-point scale
constexpr float QInv = 1.0f / QS;

__device__ __forceinline__ unsigned short f2bf_rtn(float f) {
    unsigned u = __float_as_uint(f);
    u += 0x7FFFu + ((u >> 16) & 1u);     // round-to-nearest-even
    return (unsigned short)(u >> 16);
}
__device__ __forceinline__ float bf2f(unsigned short s) {
    return __uint_as_float(((unsigned)s) << 16);
}

// ---- x -> bf16 table ----
__global__ void cvt_kernel(const float* __restrict__ x, unsigned short* __restrict__ xbf,
                           int total) {
    int i = blockIdx.x * blockDim.x + threadIdx.x;
    if (i < total) xbf[i] = f2bf_rtn(x[i]);
}

// ---- Pass 1: per-block bucket histogram ----
__global__ void count_kernel(const int* __restrict__ dst, int* __restrict__ blockCnt,
                             int E, int B, int chunk) {
    __shared__ int hist[MAXB];
    int t = threadIdx.x;  // 256
    for (int b = t; b < B; b += 256) hist[b] = 0;
    __syncthreads();
    int base = blockIdx.x * chunk;
    int end = min(base + chunk, E);
    for (int e = base + t; e < end; e += 256)
        atomicAdd(&hist[dst[e] >> LOG_NPB], 1);
    __syncthreads();
    for (int b = t; b < B; b += 256)
        blockCnt[b * NB + blockIdx.x] = hist[b];
}

// ---- Pass 2a: per-bucket exclusive scan over blocks (in place) + totals ----
__global__ void scan_rows(int* __restrict__ blockCnt, int* __restrict__ bucketTotal, int B) {
    __shared__ int s[256];
    int t = threadIdx.x;
    int* row = blockCnt + blockIdx.x * NB;
    int carry = 0;
    for (int c = 0; c < NB; c += 256) {
        int i = c + t;
        int v = (i < NB) ? row[i] : 0;
        s[t] = v;
        __syncthreads();
        for (int off = 1; off < 256; off <<= 1) {
            int x = (t >= off) ? s[t - off] : 0;
            __syncthreads();
            s[t] += x;
            __syncthreads();
        }
        int incl = s[t];
        int total = s[255];
        __syncthreads();
        if (i < NB) row[i] = carry + incl - v;
        carry += total;
    }
    if (t == 0) bucketTotal[blockIdx.x] = carry;
}

// ---- Pass 2b: exclusive scan over bucket totals -> bucketBase[B+1] ----
__global__ void scan_buckets(const int* __restrict__ bucketTotal, int* __restrict__ bucketBase,
                             int B, int E) {
    __shared__ int s[256];
    int t = threadIdx.x;
    int carry = 0;
    for (int c = 0; c < MAXB; c += 256) {
        int i = c + t;
        int v = (i < B) ? bucketTotal[i] : 0;
        s[t] = v;
        __syncthreads();
        for (int off = 1; off < 256; off <<= 1) {
            int x = (t >= off) ? s[t - off] : 0;
            __syncthreads();
            s[t] += x;
            __syncthreads();
        }
        int incl = s[t];
        int total = s[255];
        __syncthreads();
        if (i < B) bucketBase[i] = carry + incl - v;
        carry += total;
    }
    if (t == 0) bucketBase[B] = E;
}

// ---- Pass 3: scatter packed edges into bucketed order (LDS int cursors) ----
__global__ void partition_kernel(const int* __restrict__ src, const int* __restrict__ dst,
                                 const int* __restrict__ blockCnt,
                                 const int* __restrict__ bucketBase,
                                 unsigned* __restrict__ ebuf, int E, int B, int chunk) {
    __shared__ int cursor[MAXB];
    int t = threadIdx.x;  // 256
    for (int b = t; b < B; b += 256)
        cursor[b] = bucketBase[b] + blockCnt[b * NB + blockIdx.x];
    __syncthreads();
    int base = blockIdx.x * chunk;
    int end = min(base + chunk, E);
    for (int e = base + t; e < end; e += 256) {
        int d = dst[e];
        int bkt = d >> LOG_NPB;
        int pos = atomicAdd(&cursor[bkt], 1);
        ebuf[pos] = ((unsigned)(d & (NPB - 1)) << SRC_BITS) | (unsigned)src[e];
    }
}

// ---- Fused SAGE layer: one block (256 thr = 8 groups x 32 lanes) per bucket ----
// Gathers bf16 rows (64B/line), accumulates Q18 int via native LDS int atomics.
template <int WRITE_BF16>
__global__ __launch_bounds__(256, 4)
void sage_bucket(const unsigned short* __restrict__ tbl,   // bf16 node features
                 const int* __restrict__ bucketBase,
                 const unsigned* __restrict__ ebuf,
                 const float* __restrict__ Wl, const float* __restrict__ Wr,
                 const float* __restrict__ bias,
                 float* __restrict__ outF, unsigned short* __restrict__ outB,
                 int n) {
    __shared__ int accI[(NPB + 1) * D];      // 8.125 KB (+1 trash row for pads)
    __shared__ unsigned stage[STAGE];        // 4 KB; reused as xloc in epilogue
    __shared__ float sWl[D * D];             // 4 KB
    __shared__ float sWr[D * D];             // 4 KB
    __shared__ int cntI[NPB];
    int t = threadIdx.x;
    int node0 = blockIdx.x * NPB;

    for (int i = t; i < (NPB + 1) * D; i += 256) accI[i] = 0;
    if (t < NPB) cntI[t] = 0;
#pragma unroll
    for (int i = 0; i < 4; ++i) {
        sWl[t + i * 256] = Wl[t + i * 256];
        sWr[t + i * 256] = Wr[t + i * 256];
    }

    int g = t >> 5, j = t & 31;
    int base = bucketBase[blockIdx.x];
    int end = bucketBase[blockIdx.x + 1];

    while (base < end) {
        int len = min(end - base, STAGE);
        int lenp = (len + 63) & ~63;         // pad to 64 with dummy edges
        __syncthreads();                     // previous chunk fully consumed
        for (int i = t; i < lenp; i += 256) {
            unsigned w = DUMMY;
            if (i < len) {
                w = ebuf[base + i];
                atomicAdd(&cntI[w >> SRC_BITS], 1);   // int LDS atomic: fast
            }
            stage[i] = w;
        }
        __syncthreads();
        // 8 groups x 8 edges per iteration; guard-free (padded)
        for (int k0 = g * 8; k0 < lenp; k0 += 64) {
            unsigned w[8];
            int q[8];
#pragma unroll
            for (int u = 0; u < 8; ++u) w[u] = stage[k0 + u];        // broadcast
#pragma unroll
            for (int u = 0; u < 8; ++u) {                            // 8 lines in flight
                unsigned short us = tbl[(size_t)(w[u] & SRC_MASK) * D + j];
                q[u] = __float2int_rn(bf2f(us) * QS);
            }
#pragma unroll
            for (int u = 0; u < 8; ++u)
                atomicAdd(&accI[(w[u] >> SRC_BITS) * D + j], q[u]);  // ds_add_u32
        }
        base += len;
    }

    __syncthreads();                         // all gathers done
    // in-place Q18 int -> float
    float* accF = (float*)accI;
    for (int i = t; i < NPB * D; i += 256) accF[i] = (float)accI[i] * QInv;
    // stage buffer -> this bucket's own (root) features as float
    float* xloc = (float*)stage;             // 64*32 floats = 8KB? stage is 4KB!
    // NOTE: stage is only 4KB; xloc needs 8KB. Use two halves: process 32 nodes
    // at a time to stay within the 4KB stage buffer.
    float bj = bias[j];
    __syncthreads();
#pragma unroll
    for (int half = 0; half < 2; ++half) {
        int nodeH = node0 + half * 32;
        for (int i = t; i < 32 * D; i += 256) {
            int gn = nodeH + (i >> 5);
            xloc[i] = (gn < n) ? bf2f(tbl[(size_t)nodeH * D + i]) : 0.f;
        }
        __syncthreads();
#pragma unroll
        for (int it = 0; it < 4; ++it) {     // 4 x 8 nodes = 32 nodes per half
            int dl = half * 32 + it * 8 + g;
            int gn = node0 + dl;
            if (gn < n) {
                float accA = 0.f, accX = 0.f;
                const float* ar = accF + dl * D;
                const float* xr = xloc + (it * 8 + g) * D;
#pragma unroll
                for (int k = 0; k < D; ++k) {
                    accA += ar[k] * sWl[k * D + j];
                    accX += xr[k] * sWr[k * D + j];
                }
                float rdeg = 1.f / fmaxf((float)cntI[dl], 1.f);
                float r = fmaxf(accA * rdeg + bj + accX, 0.f);
                if (WRITE_BF16) outB[(size_t)gn * D + j] = f2bf_rtn(r);
                else            outF[(size_t)gn * D + j] = r;
            }
        }
        __syncthreads();
    }
}

extern "C" void kernel_launch(void* const* d_in, const int* in_sizes, int n_in,
                              void* d_out, int out_size, void* d_ws, size_t ws_size,
                              hipStream_t stream) {
    const float* x   = (const float*)d_in[0];
    const int*   ei  = (const int*)d_in[1];
    const float* W1l = (const float*)d_in[2];
    const float* W1r = (const float*)d_in[3];
    const float* b1  = (const float*)d_in[4];
    const float* W2l = (const float*)d_in[5];
    const float* W2r = (const float*)d_in[6];
    const float* b2  = (const float*)d_in[7];
    float* out = (float*)d_out;

    const int n = in_sizes[0] / D;
    const int E = in_sizes[1] / 2;
    const int* src = ei;
    const int* dst = ei + E;
    const int B = (n + NPB - 1) >> LOG_NPB;     // 1563 for n=100000
    const int chunk = (E + NB - 1) / NB;

    // ws: blockCnt[MAXB*NB] | bucketTotal[MAXB] | bucketBase[MAXB+1] |
    //     ebuf[E] | xbf[n*D] | hbf[n*D]
    int* blockCnt    = (int*)d_ws;
    int* bucketTotal = blockCnt + (size_t)MAXB * NB;
    int* bucketBase  = bucketTotal + MAXB;
    unsigned* ebuf   = (unsigned*)(bucketBase + (MAXB + 1));
    unsigned short* xbf = (unsigned short*)(ebuf + E);
    unsigned short* hbf = xbf + (size_t)n * D;

    cvt_kernel<<<(n * D + 255) / 256, 256, 0, stream>>>(x, xbf, n * D);
    count_kernel<<<NB, 256, 0, stream>>>(dst, blockCnt, E, B, chunk);
    scan_rows<<<B, 256, 0, stream>>>(blockCnt, bucketTotal, B);
    scan_buckets<<<1, 256, 0, stream>>>(bucketTotal, bucketBase, B, E);
    partition_kernel<<<NB, 256, 0, stream>>>(src, dst, blockCnt, bucketBase, ebuf, E, B, chunk);

    sage_bucket<1><<<B, 256, 0, stream>>>(xbf, bucketBase, ebuf, W1l, W1r, b1,
                                          nullptr, hbf, n);
    sage_bucket<0><<<B, 256, 0, stream>>>(hbf, bucketBase, ebuf, W2l, W2r, b2,
                                          out, nullptr, n);
}